// Round 16
// baseline (39.150 us; speedup 1.0000x reference)
//
#include <hip/hip_runtime.h>
#include <hip/hip_bf16.h>
#include <math.h>

#define BB 64
#define CC 3
#define HH 384
#define WW 384
#define HW (HH * WW)

// Each block: 64x48 output tile of one image (3 channels), staged via LDS.
// 1024 threads = 64(x) x 16(y); each thread does 3 rows (stride 16).
// R15 = R14 + FORCED batch staging: 2 batches x 9 loads, asm keep-alive
// between loads and ds_writes so the batch actually materializes in VGPRs
// (R10/R12/R14 all silently re-serialized; VGPR_Count 24 was the tell).
#define TILE_W 64
#define TILE_H 48
#define TX_TILES (WW / TILE_W)                 // 6
#define TY_TILES (HH / TILE_H)                 // 8
#define TILES_PER_IMG (TX_TILES * TY_TILES)    // 48
#define NBLOCKS (BB * TILES_PER_IMG)           // 3072 (divisible by 8)

// Rotated bbox of 64x48 at <=15deg: LW <= 78, LH <= 66.
#define LW_STRIDE 79      // odd -> rows shift banks by 15
#define LH_MAX 66
#define NSTG 6
#define LCH (NSTG * 1024)  // 6144 >= 66*79=5214, padded for guard-free staging
// LDS = 3 * 6144 * 4 = 73728 B -> 2 blocks/CU x 16 waves = 32 waves (100%)

__global__ __launch_bounds__(1024, 8) void GeometricAugment_kernel(
    const float* __restrict__ x,
    const float* __restrict__ angles,
    const float* __restrict__ dx,
    const float* __restrict__ dy,
    float* __restrict__ out) {

    __shared__ float lds[CC * LCH];

    // XCD-chunked bijective swizzle (3072 % 8 == 0)
    int bid = blockIdx.x;
    int swz = (bid & 7) * (NBLOCKS / 8) + (bid >> 3);

    int b   = swz / TILES_PER_IMG;
    int t   = swz - b * TILES_PER_IMG;
    int tyb = t / TX_TILES;
    int txb = t - tyb * TX_TILES;

    int tid = threadIdx.x;
    int tx  = tid & 63;   // 0..63
    int tyl = tid >> 6;   // 0..15

    const int X0 = txb * TILE_W;
    const int Y0 = tyb * TILE_H;

    const float cx = (WW - 1) * 0.5f;
    const float cy = (HH - 1) * 0.5f;

    float rad = angles[b] * (float)(M_PI / 180.0);
    float si, co;
    __sincosf(rad, &si, &co);
    float txs = dx[b];
    float tys = dy[b];

    // tile-corner sample coords (uniform across block)
    float xo0 = (float)X0 - cx - txs;
    float xo1 = (float)(X0 + TILE_W - 1) - cx - txs;
    float yo0 = (float)Y0 - cy - tys;
    float yo1 = (float)(Y0 + TILE_H - 1) - cy - tys;

    float xsA = co * xo0 + si * yo0 + cx;
    float xsB = co * xo1 + si * yo0 + cx;
    float xsC = co * xo0 + si * yo1 + cx;
    float xsD = co * xo1 + si * yo1 + cx;
    float ysA = -si * xo0 + co * yo0 + cy;
    float ysB = -si * xo1 + co * yo0 + cy;
    float ysC = -si * xo0 + co * yo1 + cy;
    float ysD = -si * xo1 + co * yo1 + cy;

    float xsmin = fminf(fminf(xsA, xsB), fminf(xsC, xsD));
    float xsmax = fmaxf(fmaxf(xsA, xsB), fmaxf(xsC, xsD));
    float ysmin = fminf(fminf(ysA, ysB), fminf(ysC, ysD));
    float ysmax = fmaxf(fmaxf(ysA, ysB), fmaxf(ysC, ysD));

    int ximin = (int)floorf(xsmin) - 1;
    int yimin = (int)floorf(ysmin) - 1;

    int LH = (int)floorf(ysmax) + 2 - yimin + 1;
    LH = min(LH, LH_MAX);
    bool interior = (ximin >= 0) && (yimin >= 0) &&
                    (ximin + LW_STRIDE <= WW) && (yimin + LH <= HH);

    const float* imgb = x + (size_t)b * CC * HW;

    // ---- staging: 2 batches of 3 texel-triples (9 loads), forced live ----
    #pragma unroll
    for (int h = 0; h < 2; ++h) {
        float s0[3], s1[3], s2[3];
        #pragma unroll
        for (int kk = 0; kk < 3; ++kk) {
            int k  = h * 3 + kk;
            int i  = tid + k * 1024;            // 0..6143
            int y  = i / LW_STRIDE;             // 0..77
            int xL = i - y * LW_STRIDE;
            int gy = min(max(yimin + y, 0), HH - 1);
            int gx = min(max(ximin + xL, 0), WW - 1);
            const float* src = imgb + gy * WW + gx;
            s0[kk] = src[0];
            s1[kk] = src[HW];
            s2[kk] = src[2 * HW];
        }
        // keep-alive: force all 9 loads resident before any ds_write
        asm volatile("" ::
            "v"(s0[0]), "v"(s0[1]), "v"(s0[2]),
            "v"(s1[0]), "v"(s1[1]), "v"(s1[2]),
            "v"(s2[0]), "v"(s2[1]), "v"(s2[2]));
        #pragma unroll
        for (int kk = 0; kk < 3; ++kk) {
            int i = tid + (h * 3 + kk) * 1024;
            lds[i]           = s0[kk];
            lds[LCH + i]     = s1[kk];
            lds[2 * LCH + i] = s2[kk];
        }
    }
    __syncthreads();

    // ---- gather from LDS ----
    int x_out = X0 + tx;
    float xo = (float)x_out - cx - txs;
    float yo = (float)(Y0 + tyl) - cy - tys;

    float xs =  co * xo + si * yo + cx;
    float ys = -si * xo + co * yo + cy;
    const float dxs = 16.0f * si;
    const float dys = 16.0f * co;

    float* outb = out + (size_t)b * CC * HW + (size_t)Y0 * WW + x_out;

    if (interior) {
        #pragma unroll
        for (int r = 0; r < TILE_H / 16; ++r) {
            float x0f = floorf(xs);
            float y0f = floorf(ys);
            float wx = xs - x0f;
            float wy = ys - y0f;
            int base = ((int)y0f - yimin) * LW_STRIDE + ((int)x0f - ximin);

            #pragma unroll
            for (int c = 0; c < CC; ++c) {
                const float* l = lds + c * LCH + base;
                float v00 = l[0];
                float v01 = l[1];
                float v10 = l[LW_STRIDE];
                float v11 = l[LW_STRIDE + 1];
                float top = v00 + wx * (v01 - v00);
                float bot = v10 + wx * (v11 - v10);
                float v = top + wy * (bot - top);
                v = fminf(fmaxf(v, 0.0f), 1.0f);
                __builtin_nontemporal_store(v, outb + (size_t)c * HW + (size_t)(tyl + r * 16) * WW);
            }
            xs += dxs;
            ys += dys;
        }
    } else {
        #pragma unroll
        for (int r = 0; r < TILE_H / 16; ++r) {
            float x0f = floorf(xs);
            float y0f = floorf(ys);
            float wx = xs - x0f;
            float wy = ys - y0f;
            int x0 = (int)x0f;
            int y0 = (int)y0f;
            int x1 = x0 + 1;
            int y1 = y0 + 1;

            float vx0 = (x0 >= 0 && x0 < WW) ? 1.0f : 0.0f;
            float vx1 = (x1 >= 0 && x1 < WW) ? 1.0f : 0.0f;
            float vy0 = (y0 >= 0 && y0 < HH) ? 1.0f : 0.0f;
            float vy1 = (y1 >= 0 && y1 < HH) ? 1.0f : 0.0f;

            float w00 = (1.0f - wx) * (1.0f - wy) * vx0 * vy0;
            float w01 = wx * (1.0f - wy) * vx1 * vy0;
            float w10 = (1.0f - wx) * wy * vx0 * vy1;
            float w11 = wx * wy * vx1 * vy1;

            int base = (y0 - yimin) * LW_STRIDE + (x0 - ximin);

            #pragma unroll
            for (int c = 0; c < CC; ++c) {
                const float* l = lds + c * LCH + base;
                float v00 = l[0];
                float v01 = l[1];
                float v10 = l[LW_STRIDE];
                float v11 = l[LW_STRIDE + 1];
                float v = v00 * w00 + v01 * w01 + v10 * w10 + v11 * w11;
                v = fminf(fmaxf(v, 0.0f), 1.0f);
                __builtin_nontemporal_store(v, outb + (size_t)c * HW + (size_t)(tyl + r * 16) * WW);
            }
            xs += dxs;
            ys += dys;
        }
    }
}

extern "C" void kernel_launch(void* const* d_in, const int* in_sizes, int n_in,
                              void* d_out, int out_size, void* d_ws, size_t ws_size,
                              hipStream_t stream) {
    const float* x      = (const float*)d_in[0];
    const float* angles = (const float*)d_in[1];
    const float* dx     = (const float*)d_in[2];
    const float* dy     = (const float*)d_in[3];
    float* out = (float*)d_out;

    GeometricAugment_kernel<<<NBLOCKS, 1024, 0, stream>>>(x, angles, dx, dy, out);
}